// Round 16
// baseline (253.138 us; speedup 1.0000x reference)
//
#include <hip/hip_runtime.h>

#define T_ 32
#define B_ 32
#define H_ 128
#define W_ 128
#define C_ 2
#define NP_ 256
#define CF_ 64
#define CP_ 32
#define OUT_ 128

// padded periph image: rows -1..64 (66), px -2..65 (68) * 2ch = 136 floats/row
#define PROW 136
#define PTB  8976    // 66*136 floats per (t,b)
// padded fovea window: 34 rows x 34 px x 2ch = 2312 floats per (t,b)
#define WTB  2312

// d_out layout (floats): out(4096) | logits_seq(131072) | sr(2) | active(1) | route(256) | chan(64)
#define OFF_LOGITS 4096
#define OFF_SR     135168
#define OFF_ACTIVE 135170
#define OFF_ROUTE  135171
#define OFF_CHAN   135427

// ws_cnt layout (u32): [0]=active  [1..256]=route  [257..320]=chan  [321]=totf  [322]=totp
#define CNT_N 323

typedef float f2 __attribute__((ext_vector_type(2)));

__device__ __forceinline__ float f4c(const float4& v, int i) {
  switch (i & 3) { case 0: return v.x; case 1: return v.y; case 2: return v.z; default: return v.w; }
}

// ---------------- K1: per-(t,b) everything pre-membrane ----------------
__global__ void __launch_bounds__(256) k_pre(const float* __restrict__ x,
    const float* __restrict__ wf,
    float* __restrict__ scores_g, float* __restrict__ P, float* __restrict__ Wfbuf,
    float* __restrict__ chan_gate, unsigned* __restrict__ cnts) {
  const int tb = blockIdx.x, tid = threadIdx.x;
  __shared__ __align__(16) float xt[34*256];   // staging / later fovea tile
  __shared__ float sm[NP_];
  __shared__ float salred[512];
  __shared__ float salv[64];
  __shared__ unsigned wsum[4];
  __shared__ float wred[4];
  __shared__ int widx[4];
  __shared__ int2 syx;
  const float* img = x + (size_t)tb*32768;
  unsigned cnt = 0;
  for (int chunk = 0; chunk < 4; ++chunk) {
    const int r0 = chunk*16;
    __syncthreads();                    // xt safe to overwrite
    for (int i4 = tid; i4 < 34*64; i4 += 256) {
      const int rr = i4 >> 6, off4 = i4 & 63;
      const int xr = 2*r0 - 1 + rr;
      float4 vv = make_float4(0.f, 0.f, 0.f, 0.f);
      if (xr >= 0 && xr < H_) {
        vv = *reinterpret_cast<const float4*>(img + (size_t)xr*256 + off4*4);
        if (rr >= 1 && rr <= 32) {
          cnt += (fabsf(vv.x) > 0.5f) + (fabsf(vv.y) > 0.5f)
               + (fabsf(vv.z) > 0.5f) + (fabsf(vv.w) > 0.5f);
        }
        vv.x = (fabsf(vv.x) > 0.5f) ? vv.x : 0.f;
        vv.y = (fabsf(vv.y) > 0.5f) ? vv.y : 0.f;
        vv.z = (fabsf(vv.z) > 0.5f) ? vv.z : 0.f;
        vv.w = (fabsf(vv.w) > 0.5f) ? vv.w : 0.f;
      }
      *reinterpret_cast<float4*>(&xt[i4*4]) = vv;
    }
    __syncthreads();
    // ---- patch scores ----
    {
      const int patch = tid >> 2, q = tid & 3;
      const int prl = patch >> 4, pc = patch & 15;
      const int row = 1 + prl*8 + q*2;
      float s = 0.f;
#pragma unroll
      for (int r2 = 0; r2 < 2; ++r2)
#pragma unroll
        for (int j = 0; j < 4; ++j) {
          const float4 vv = *reinterpret_cast<const float4*>(&xt[(row + r2)*256 + pc*16 + j*4]);
          s += fabsf(vv.x) + fabsf(vv.y) + fabsf(vv.z) + fabsf(vv.w);
        }
      s += __shfl_down(s, 1);
      s += __shfl_down(s, 2);
      if (q == 0) {
        const float sv = s * (1.f/128.f);
        sm[chunk*64 + patch] = sv;
        scores_g[tb*NP_ + chunk*64 + patch] = sv;
      }
    }
    // ---- padded downsample (f2 over channel pair) ----
    float* Pt = P + (size_t)tb * PTB;
    if (tid < 128) {
      const int r = tid >> 3, rem = tid & 7;
      const int px4 = rem >> 1, ci = rem & 1;
      const int px = (px4 < 2) ? (px4 - 2) : (62 + px4);
      Pt[(r0 + r + 1)*PROW + (px + 2)*2 + ci] = 0.f;
    }
    if (chunk == 0 && tid < PROW) Pt[tid] = 0.f;
    if (chunk == 3 && tid < PROW) Pt[65*PROW + tid] = 0.f;
#pragma unroll
    for (int k = 0; k < 4; ++k) {
      const int idx = k*256 + tid;       // f2 output: row16*64 + col
      const int col = idx & 63, row16 = idx >> 6;
      const int pr = r0 + row16;
      float wy0=0.125f, wy1=0.375f, wy2=0.375f, wy3=0.125f;
      if (pr == 0)       { wy0=0.f;     wy1=3.f/7.f; wy2=3.f/7.f; wy3=1.f/7.f; }
      else if (pr == 63) { wy0=1.f/7.f; wy1=3.f/7.f; wy2=3.f/7.f; wy3=0.f; }
      float wx0=0.125f, wx1=0.375f, wx2=0.375f, wx3=0.125f;
      if (col == 0)       { wx0=0.f;     wx1=3.f/7.f; wx2=3.f/7.f; wx3=1.f/7.f; }
      else if (col == 63) { wx0=1.f/7.f; wx1=3.f/7.f; wx2=3.f/7.f; wx3=0.f; }
      const int lr = 2*row16;
      const int cc0 = 2*col - 1;
      f2 val = (f2)0.f;
#pragma unroll
      for (int j = 0; j < 4; ++j) {
        const float wyj = (j==0)?wy0:(j==1)?wy1:(j==2)?wy2:wy3;
        f2 h = (f2)0.f;
#pragma unroll
        for (int i = 0; i < 4; ++i) {
          const float wxi = (i==0)?wx0:(i==1)?wx1:(i==2)?wx2:wx3;
          int cc = cc0 + i; cc = cc < 0 ? 0 : (cc > W_-1 ? W_-1 : cc);
          const f2 xv = *reinterpret_cast<const f2*>(&xt[(lr + j)*256 + cc*2]);
          h += wxi * xv;
        }
        val += wyj * h;
      }
      *reinterpret_cast<f2*>(&Pt[(pr + 1)*PROW + (col + 2)*2]) = val;
    }
  }
  // ---- event-count reduce ----
  unsigned c64 = cnt;
#pragma unroll
  for (int off = 32; off > 0; off >>= 1) c64 += __shfl_down(c64, off);
  if ((tid & 63) == 0) wsum[tid >> 6] = c64;
  __syncthreads();
  if (tid == 0) atomicAdd(&cnts[0], wsum[0] + wsum[1] + wsum[2] + wsum[3]);
  // ---- top-4 threshold + first-index argmax (tournament) ----
  {
    const float sv_ = sm[tid];
    const int wv = tid >> 6, ln = tid & 63;
    bool masked = false;
    float v4 = 0.f;
    for (int r = 0; r < 4; ++r) {
      float cur = masked ? -1e30f : sv_;
      float m = cur;
#pragma unroll
      for (int off = 32; off > 0; off >>= 1) m = fmaxf(m, __shfl_xor(m, off));
      if (ln == 0) wred[wv] = m;
      __syncthreads();
      const float bm = fmaxf(fmaxf(wred[0], wred[1]), fmaxf(wred[2], wred[3]));
      const unsigned long long eq = __ballot(cur == bm);
      if (ln == 0) widx[wv] = eq ? (wv*64 + (int)(__ffsll((long long)eq) - 1)) : 1024;
      __syncthreads();
      const int first = min(min(widx[0], widx[1]), min(widx[2], widx[3]));
      if (tid == first) {
        masked = true;
        if (r == 0) {
          const int cy = (tid >> 4)*8 + 4, cx = (tid & 15)*8 + 4;
          int y0 = cy - 16; y0 = y0 < 0 ? 0 : (y0 > 96 ? 96 : y0);
          int x0 = cx - 16; x0 = x0 < 0 ? 0 : (x0 > 96 ? 96 : x0);
          syx = make_int2(y0, x0);
        }
      }
      if (r == 3) v4 = bm;
      __syncthreads();
    }
    if (sv_ >= v4) atomicAdd(&cnts[1 + tid], 1u);
  }
  // ---- zero fovea tile (reuse xt as tile[34*68]) ----
  float* tile = xt;
  for (int i = tid; i < 34*68; i += 256) tile[i] = 0.f;
  __syncthreads();
  const int2 yx = syx;
  {                                     // fill interior: 32 rows x 8 segs x 4px
    const int row = tid >> 3, seg = tid & 7;
    const float* src = img + (size_t)(yx.x + row)*256 + (yx.y + seg*4)*2;
    float4 a = *reinterpret_cast<const float4*>(src);
    float4 b4 = *reinterpret_cast<const float4*>(src + 4);
    a.x  = (fabsf(a.x)  > 0.5f) ? a.x  : 0.f;
    a.y  = (fabsf(a.y)  > 0.5f) ? a.y  : 0.f;
    a.z  = (fabsf(a.z)  > 0.5f) ? a.z  : 0.f;
    a.w  = (fabsf(a.w)  > 0.5f) ? a.w  : 0.f;
    b4.x = (fabsf(b4.x) > 0.5f) ? b4.x : 0.f;
    b4.y = (fabsf(b4.y) > 0.5f) ? b4.y : 0.f;
    b4.z = (fabsf(b4.z) > 0.5f) ? b4.z : 0.f;
    b4.w = (fabsf(b4.w) > 0.5f) ? b4.w : 0.f;
    float* dst = &tile[(row + 1)*68 + (seg*4 + 1)*2];
    *reinterpret_cast<float2*>(dst)     = make_float2(a.x, a.y);
    *reinterpret_cast<float2*>(dst + 2) = make_float2(a.z, a.w);
    *reinterpret_cast<float2*>(dst + 4) = make_float2(b4.x, b4.y);
    *reinterpret_cast<float2*>(dst + 6) = make_float2(b4.z, b4.w);
  }
  __syncthreads();
  {                                     // dump padded masked window for k_mem
    float* dst = Wfbuf + (size_t)tb*WTB;
    for (int i = tid; i < WTB/4; i += 256)
      *reinterpret_cast<float4*>(dst + i*4) = *reinterpret_cast<const float4*>(&tile[i*4]);
  }
  // ---- fovea conv -> saliency (pk-f32, 2ch/thread, 4px groups) ----
  const int cp2 = tid & 31, xg = tid >> 5;       // ch-pair, x-group of 4 px
  const int c0 = cp2*2;
  f2 wxr[9], wyr[9];
#pragma unroll
  for (int j = 0; j < 9; ++j) {
    wxr[j] = *reinterpret_cast<const f2*>(&wf[(2*j)*CF_ + c0]);
    wyr[j] = *reinterpret_cast<const f2*>(&wf[(2*j + 1)*CF_ + c0]);
  }
  const float* tbase = &tile[xg*8];
  float4 wb[3][3];
#pragma unroll
  for (int m = 0; m < 3; ++m) {
    wb[0][m] = *reinterpret_cast<const float4*>(tbase + m*4);
    wb[1][m] = *reinterpret_cast<const float4*>(tbase + 68 + m*4);
  }
  f2 sal = (f2)0.f;
#pragma unroll
  for (int yy = 0; yy < 32; ++yy) {
#pragma unroll
    for (int m = 0; m < 3; ++m)
      wb[(yy+2)%3][m] = *reinterpret_cast<const float4*>(tbase + (yy+2)*68 + m*4);
#pragma unroll
    for (int k = 0; k < 4; ++k) {
      f2 acc = (f2)0.f;
#pragma unroll
      for (int dy = 0; dy < 3; ++dy) {
#pragma unroll
        for (int dx = 0; dx < 3; ++dx) {
          const int r = k + dx;
          const float4 f = wb[(yy+dy)%3][r >> 1];
          acc += f4c(f, (r&1)*2)     * wxr[dy*3+dx]
               + f4c(f, (r&1)*2 + 1) * wyr[dy*3+dx];
        }
      }
      sal.x += fabsf(acc.x);
      sal.y += fabsf(acc.y);
    }
  }
  salred[xg*64 + c0]     = sal.x;
  salred[xg*64 + c0 + 1] = sal.y;
  __syncthreads();
  if (tid < 64) {
    float s = 0.f;
#pragma unroll
    for (int g = 0; g < 8; ++g) s += salred[g*64 + tid];
    salv[tid] = s * (1.f/1024.f);
  }
  __syncthreads();
  if (tid < 64) {
    const float sv = salv[tid];
    int cg = 0;
    for (int q = 0; q < 64; ++q) cg += (salv[q] > sv) ? 1 : 0;
    const float gate = (cg < 16) ? 1.f : 0.f;
    chan_gate[tb*CF_ + tid] = gate;
    if (gate > 0.f) atomicAdd(&cnts[257 + tid], 1u);
  }
}

// ---------------- K2: persistent membranes, LDS slab dbuf, 4 ch/thread ----------------
// fovea:  blocks 0..1023    = b*32 + cp*2 + half (cp 0..15, 4ch); 2px/lane, slab 18x68
// periph: blocks 1024..2047 = 1024 + b*32 + cp*4 + rq (cp 0..7, 4ch; rq 0..3, 16 rows);
//         4px/lane, slab 18x136. Grid = 2048 = exactly 8 blocks/CU.
// fov_part: u32 [t][b][cp32][8]   per_part: u32 [t][b][cp16][16]
__global__ void __launch_bounds__(256, 2) k_mem(const float* __restrict__ Wfbuf,
    const float* __restrict__ P, const float* __restrict__ wf, const float* __restrict__ wp,
    const float* __restrict__ chan_gate,
    unsigned* __restrict__ fov_part, unsigned* __restrict__ per_part) {
  __shared__ __align__(16) float lds[2*2448];
  const int tid = threadIdx.x;
  const int w = tid >> 6, l = tid & 63;
  int zp;                               // opaque zero: forces weight/gate loads into VGPRs
  asm volatile("v_mov_b32 %0, 0" : "=v"(zp));
  if (blockIdx.x < 1024) {
    const int blk = blockIdx.x;
    const int b = blk >> 5, rem = blk & 31, cp = rem >> 1, half = rem & 1;
    const int ch0 = cp*4;
    const int brow = w*4 + (l >> 4);
    const int po = (l & 15)*4;
    f2 w01[18], w23[18];
#pragma unroll
    for (int k = 0; k < 18; ++k) {
      w01[k] = *reinterpret_cast<const f2*>(&wf[k*CF_ + ch0 + zp]);
      w23[k] = *reinterpret_cast<const f2*>(&wf[k*CF_ + ch0 + zp + 2]);
    }
    const float* gsrc = Wfbuf + (size_t)b*WTB + half*16*68;   // 1224 floats/slab
    const float* gp = chan_gate + b*CF_ + ch0 + zp;
    const unsigned ob01 = (unsigned)((b*32 + cp*2)*8 + half*4 + w);
    f2 va01 = (f2)0.f, vb01 = (f2)0.f, va23 = (f2)0.f, vb23 = (f2)0.f;
    float4 r0, r1;
    r0 = *reinterpret_cast<const float4*>(gsrc + tid*4);
    if (tid < 50) r1 = *reinterpret_cast<const float4*>(gsrc + (tid + 256)*4);
    *reinterpret_cast<float4*>(&lds[tid*4]) = r0;
    if (tid < 50) *reinterpret_cast<float4*>(&lds[(tid + 256)*4]) = r1;
    int cur = 0;
    for (int t = 0; t < T_; ++t) {
      __syncthreads();                  // slab[cur] visible to all
      if (t + 1 < T_) {                 // issue next slab's loads early
        const float* gn = gsrc + (size_t)(t + 1)*(B_*WTB);
        r0 = *reinterpret_cast<const float4*>(gn + tid*4);
        if (tid < 50) r1 = *reinterpret_cast<const float4*>(gn + (tid + 256)*4);
      }
      __builtin_amdgcn_sched_barrier(0);
      const f2 g01 = *reinterpret_cast<const f2*>(gp + (size_t)t*B_*CF_);
      const f2 g23 = *reinterpret_cast<const f2*>(gp + (size_t)t*B_*CF_ + 2);
      const float* Lb = &lds[cur*2448];
      f2 aa01 = (f2)0.f, ab01 = (f2)0.f, aa23 = (f2)0.f, ab23 = (f2)0.f;
#pragma unroll
      for (int dy = 0; dy < 3; ++dy) {
        const float4 fa = *reinterpret_cast<const float4*>(Lb + (brow + dy)*68 + po);
        const float4 fb = *reinterpret_cast<const float4*>(Lb + (brow + dy)*68 + po + 4);
        {
          const f2 w0 = w01[dy*6], w0y = w01[dy*6+1], w1 = w01[dy*6+2],
                   w1y = w01[dy*6+3], w2 = w01[dy*6+4], w2y = w01[dy*6+5];
          aa01 += fa.x*w0 + fa.y*w0y + fa.z*w1 + fa.w*w1y + fb.x*w2 + fb.y*w2y;
          ab01 += fa.z*w0 + fa.w*w0y + fb.x*w1 + fb.y*w1y + fb.z*w2 + fb.w*w2y;
        }
        {
          const f2 w0 = w23[dy*6], w0y = w23[dy*6+1], w1 = w23[dy*6+2],
                   w1y = w23[dy*6+3], w2 = w23[dy*6+4], w2y = w23[dy*6+5];
          aa23 += fa.x*w0 + fa.y*w0y + fa.z*w1 + fa.w*w1y + fb.x*w2 + fb.y*w2y;
          ab23 += fa.z*w0 + fa.w*w0y + fb.x*w1 + fb.y*w1y + fb.z*w2 + fb.w*w2y;
        }
      }
      f2 na01 = 0.9f*va01 + aa01*g01;
      f2 nb01 = 0.9f*vb01 + ab01*g01;
      f2 na23 = 0.9f*va23 + aa23*g23;
      f2 nb23 = 0.9f*vb23 + ab23*g23;
      const bool s0a = na01.x > 1.f, s1a = na01.y > 1.f, s0b = nb01.x > 1.f, s1b = nb01.y > 1.f;
      const bool s2a = na23.x > 1.f, s3a = na23.y > 1.f, s2b = nb23.x > 1.f, s3b = nb23.y > 1.f;
      va01.x = s0a ? na01.x - 1.f : na01.x;  va01.y = s1a ? na01.y - 1.f : na01.y;
      vb01.x = s0b ? nb01.x - 1.f : nb01.x;  vb01.y = s1b ? nb01.y - 1.f : nb01.y;
      va23.x = s2a ? na23.x - 1.f : na23.x;  va23.y = s3a ? na23.y - 1.f : na23.y;
      vb23.x = s2b ? nb23.x - 1.f : nb23.x;  vb23.y = s3b ? nb23.y - 1.f : nb23.y;
      const unsigned p01 =
          (unsigned)(__popcll(__ballot(s0a)) + __popcll(__ballot(s0b)))
        | ((unsigned)(__popcll(__ballot(s1a)) + __popcll(__ballot(s1b))) << 16);
      const unsigned p23 =
          (unsigned)(__popcll(__ballot(s2a)) + __popcll(__ballot(s2b)))
        | ((unsigned)(__popcll(__ballot(s3a)) + __popcll(__ballot(s3b))) << 16);
      if (l == 0) {
        fov_part[ob01 + (unsigned)t*8192u]     = p01;
        fov_part[ob01 + 8 + (unsigned)t*8192u] = p23;
      }
      if (t + 1 < T_) {                 // write staged regs to other buffer
        float* Lw = &lds[(cur ^ 1)*2448];
        *reinterpret_cast<float4*>(Lw + tid*4) = r0;
        if (tid < 50) *reinterpret_cast<float4*>(Lw + (tid + 256)*4) = r1;
      }
      cur ^= 1;
    }
  } else {
    const int blk = blockIdx.x - 1024;
    const int b = blk >> 5, rem = blk & 31, cp = rem >> 2, rq = rem & 3;
    const int ch0 = cp*4;
    const int srow = w*4 + (l >> 4);          // slab output row 0..15
    const int po = (l & 15)*8;                // first loaded float within slab row
    f2 w01[18], w23[18];
#pragma unroll
    for (int k = 0; k < 18; ++k) {
      w01[k] = *reinterpret_cast<const f2*>(&wp[k*CP_ + ch0 + zp]);
      w23[k] = *reinterpret_cast<const f2*>(&wp[k*CP_ + ch0 + zp + 2]);
    }
    const float* gsrc = P + (size_t)b*PTB + rq*16*PROW;       // 2448 floats/slab
    const unsigned ob = (unsigned)((b*16 + cp*2)*16 + rq*4 + w);
    f2 va01[4], va23[4];
#pragma unroll
    for (int k = 0; k < 4; ++k) { va01[k] = (f2)0.f; va23[k] = (f2)0.f; }
    float4 r0, r1, r2;
    r0 = *reinterpret_cast<const float4*>(gsrc + tid*4);
    r1 = *reinterpret_cast<const float4*>(gsrc + (tid + 256)*4);
    if (tid < 100) r2 = *reinterpret_cast<const float4*>(gsrc + (tid + 512)*4);
    *reinterpret_cast<float4*>(&lds[tid*4]) = r0;
    *reinterpret_cast<float4*>(&lds[(tid + 256)*4]) = r1;
    if (tid < 100) *reinterpret_cast<float4*>(&lds[(tid + 512)*4]) = r2;
    int cur = 0;
    for (int t = 0; t < T_; ++t) {
      __syncthreads();
      if (t + 1 < T_) {
        const float* gn = gsrc + (size_t)(t + 1)*(B_*PTB);
        r0 = *reinterpret_cast<const float4*>(gn + tid*4);
        r1 = *reinterpret_cast<const float4*>(gn + (tid + 256)*4);
        if (tid < 100) r2 = *reinterpret_cast<const float4*>(gn + (tid + 512)*4);
      }
      __builtin_amdgcn_sched_barrier(0);
      const float* Lb = &lds[cur*2448];
      f2 a01[4], a23[4];
#pragma unroll
      for (int k = 0; k < 4; ++k) { a01[k] = (f2)0.f; a23[k] = (f2)0.f; }
#pragma unroll
      for (int dy = 0; dy < 3; ++dy) {
        float4 F[4];
#pragma unroll
        for (int m = 0; m < 4; ++m)
          F[m] = *reinterpret_cast<const float4*>(Lb + (srow + dy)*136 + po + m*4);
#pragma unroll
        for (int k = 0; k < 4; ++k)
#pragma unroll
          for (int dx = 0; dx < 3; ++dx) {
            const int e = 2*(k + dx + 1);
            const float cx = f4c(F[e >> 2], e & 3);
            const float cy = f4c(F[(e + 1) >> 2], (e + 1) & 3);
            a01[k] += cx*w01[dy*6 + dx*2] + cy*w01[dy*6 + dx*2 + 1];
            a23[k] += cx*w23[dy*6 + dx*2] + cy*w23[dy*6 + dx*2 + 1];
          }
      }
      unsigned c0 = 0, c1 = 0, c2 = 0, c3 = 0;
#pragma unroll
      for (int k = 0; k < 4; ++k) {
        f2 n01 = 0.9f*va01[k] + a01[k];
        f2 n23 = 0.9f*va23[k] + a23[k];
        const bool b0 = n01.x > 1.f, b1 = n01.y > 1.f, b2 = n23.x > 1.f, b3 = n23.y > 1.f;
        va01[k].x = b0 ? n01.x - 1.f : n01.x;
        va01[k].y = b1 ? n01.y - 1.f : n01.y;
        va23[k].x = b2 ? n23.x - 1.f : n23.x;
        va23[k].y = b3 ? n23.y - 1.f : n23.y;
        c0 += (unsigned)__popcll(__ballot(b0));
        c1 += (unsigned)__popcll(__ballot(b1));
        c2 += (unsigned)__popcll(__ballot(b2));
        c3 += (unsigned)__popcll(__ballot(b3));
      }
      if (l == 0) {
        per_part[ob + (unsigned)t*8192u]      = c0 | (c1 << 16);
        per_part[ob + 16 + (unsigned)t*8192u] = c2 | (c3 << 16);
      }
      if (t + 1 < T_) {
        float* Lw = &lds[(cur ^ 1)*2448];
        *reinterpret_cast<float4*>(Lw + tid*4) = r0;
        *reinterpret_cast<float4*>(Lw + (tid + 256)*4) = r1;
        if (tid < 100) *reinterpret_cast<float4*>(Lw + (tid + 512)*4) = r2;
      }
      cur ^= 1;
    }
  }
}

// ---------------- K3: reduce partials + logits ----------------
__global__ void __launch_bounds__(256) k_logits(const float* __restrict__ scores,
    const unsigned* __restrict__ fov_part, const unsigned* __restrict__ per_part,
    const float* __restrict__ head_w, const float* __restrict__ head_b,
    const float* __restrict__ route_w, const float* __restrict__ route_b,
    float* __restrict__ logits, unsigned* __restrict__ tot) {
  const int tb = blockIdx.x, tid = threadIdx.x;
  __shared__ float sc[NP_];
  __shared__ float fu[96];
  sc[tid] = scores[tb*NP_ + tid];
  if (tid < 64) {
    const unsigned* fp = fov_part + (size_t)tb*256;   // 32 cp * 8
    const int cp = tid >> 1, sh = (tid & 1)*16;
    unsigned fsum = 0;
#pragma unroll
    for (int i = 0; i < 8; ++i) fsum += (fp[cp*8 + i] >> sh) & 0xFFFFu;
    fu[tid] = (float)fsum * (1.f/1024.f);
    unsigned r = fsum;
#pragma unroll
    for (int off = 32; off > 0; off >>= 1) r += __shfl_down(r, off);
    if (tid == 0) atomicAdd(&tot[0], r);
  } else if (tid < 128) {
    const int c = tid - 64;            // only c<32 active
    unsigned psum = 0;
    if (c < 32) {
      const unsigned* pp = per_part + (size_t)tb*256;  // 16 cp * 16
      const int cp = c >> 1, sh = (c & 1)*16;
#pragma unroll 8
      for (int i = 0; i < 16; ++i) psum += (pp[cp*16 + i] >> sh) & 0xFFFFu;
      fu[64 + c] = (float)psum * (1.f/4096.f);
    }
    unsigned r = psum;
#pragma unroll
    for (int off = 32; off > 0; off >>= 1) r += __shfl_down(r, off);
    if (tid == 64) atomicAdd(&tot[1], r);
  }
  __syncthreads();
  if (tid < 128) {
    const int o = tid;
    float acc = head_b[o] + route_b[o];
#pragma unroll 8
    for (int k = 0; k < 96; ++k)  acc += fu[k]*head_w[k*OUT_ + o];
#pragma unroll 8
    for (int p = 0; p < NP_; ++p) acc += sc[p]*route_w[p*OUT_ + o];
    logits[tb*OUT_ + o] = acc;
  }
}

// ---------------- K4: finalize ----------------
__global__ void __launch_bounds__(256) k_final(const float* __restrict__ logits,
    float* __restrict__ dout, const unsigned* __restrict__ cnts) {
  const int blk = blockIdx.x, tid = threadIdx.x;
  if (blk < 16) {
    const int idx = blk*256 + tid;
    const int b = idx >> 7, o = idx & 127;
    float s = 0.f;
#pragma unroll
    for (int t = 0; t < T_; ++t) s += logits[(t*B_ + b)*OUT_ + o];
    dout[idx] = s * (1.f/32.f);
  } else {
    if (tid == 0) {
      dout[OFF_SR]     = (float)cnts[321] * (1.f/67108864.f);   // T*B*32*32*64
      dout[OFF_SR + 1] = (float)cnts[322] * (1.f/134217728.f);  // T*B*64*64*32
      dout[OFF_ACTIVE] = (float)cnts[0]   * (1.f/33554432.f);   // T*B*H*W*C
    }
    dout[OFF_ROUTE + tid] = (float)cnts[1 + tid] * (1.f/1024.f);
    if (tid < 64) dout[OFF_CHAN + tid] = (float)cnts[257 + tid] * (1.f/1024.f);
  }
}

extern "C" void kernel_launch(void* const* d_in, const int* in_sizes, int n_in,
                              void* d_out, int out_size, void* d_ws, size_t ws_size,
                              hipStream_t stream) {
  const float* x       = (const float*)d_in[0];
  const float* wf      = (const float*)d_in[1];
  const float* wp      = (const float*)d_in[2];
  const float* head_w  = (const float*)d_in[3];
  const float* head_b  = (const float*)d_in[4];
  const float* route_w = (const float*)d_in[5];
  const float* route_b = (const float*)d_in[6];
  float* out = (float*)d_out;

  float*    ws_P      = (float*)d_ws;                         // 1024*8976 floats (36.8 MB)
  float*    ws_Wf     = ws_P + (size_t)1024*PTB;              // 1024*2312 floats (9.5 MB)
  float*    ws_scores = ws_Wf + (size_t)1024*WTB;             // 262144 floats
  float*    ws_gate   = ws_scores + T_*B_*NP_;                // 65536 floats
  unsigned* fov_part  = (unsigned*)(ws_gate + T_*B_*CF_);     // 32*32*32*8 u32 (1 MB)
  unsigned* per_part  = fov_part + (size_t)T_*B_*256;         // 32*32*16*16 u32 (1 MB)
  unsigned* ws_cnt    = per_part + (size_t)T_*B_*256;

  hipMemsetAsync(ws_cnt, 0, CNT_N*sizeof(unsigned), stream);

  k_pre   <<<T_*B_, 256, 0, stream>>>(x, wf, ws_scores, ws_P, ws_Wf, ws_gate, ws_cnt);
  k_mem   <<<2048,  256, 0, stream>>>(ws_Wf, ws_P, wf, wp, ws_gate, fov_part, per_part);
  k_logits<<<T_*B_, 256, 0, stream>>>(ws_scores, fov_part, per_part, head_w, head_b,
                                      route_w, route_b, out + OFF_LOGITS, ws_cnt + 321);
  k_final <<<17, 256, 0, stream>>>(out + OFF_LOGITS, out, ws_cnt);
}

// Round 17
// 238.031 us; speedup vs baseline: 1.0635x; 1.0635x over previous
//
#include <hip/hip_runtime.h>

#define T_ 32
#define B_ 32
#define H_ 128
#define W_ 128
#define C_ 2
#define NP_ 256
#define CF_ 64
#define CP_ 32
#define OUT_ 128

// padded periph image: rows -1..64 (66), px -2..65 (68) * 2ch = 136 floats/row
#define PROW 136
#define PTB  8976    // 66*136 floats per (t,b)
// padded fovea window: 34 rows x 34 px x 2ch = 2312 floats per (t,b)
#define WTB  2312

// d_out layout (floats): out(4096) | logits_seq(131072) | sr(2) | active(1) | route(256) | chan(64)
#define OFF_LOGITS 4096
#define OFF_SR     135168
#define OFF_ACTIVE 135170
#define OFF_ROUTE  135171
#define OFF_CHAN   135427

// ws_cnt layout (u32): [0]=active  [1..256]=route  [257..320]=chan  [321]=totf  [322]=totp
#define CNT_N 323

typedef float f2 __attribute__((ext_vector_type(2)));

__device__ __forceinline__ float f4c(const float4& v, int i) {
  switch (i & 3) { case 0: return v.x; case 1: return v.y; case 2: return v.z; default: return v.w; }
}

// ---------------- K1: per-(t,b) everything pre-membrane ----------------
__global__ void __launch_bounds__(256) k_pre(const float* __restrict__ x,
    const float* __restrict__ wf,
    float* __restrict__ scores_g, float* __restrict__ P, float* __restrict__ Wfbuf,
    float* __restrict__ chan_gate, unsigned* __restrict__ cnts) {
  const int tb = blockIdx.x, tid = threadIdx.x;
  __shared__ __align__(16) float xt[34*256];   // staging / later fovea tile
  __shared__ float sm[NP_];
  __shared__ float salred[512];
  __shared__ float salv[64];
  __shared__ unsigned wsum[4];
  __shared__ float wred[4];
  __shared__ int widx[4];
  __shared__ int2 syx;
  const float* img = x + (size_t)tb*32768;
  unsigned cnt = 0;
  for (int chunk = 0; chunk < 4; ++chunk) {
    const int r0 = chunk*16;
    __syncthreads();                    // xt safe to overwrite
    for (int i4 = tid; i4 < 34*64; i4 += 256) {
      const int rr = i4 >> 6, off4 = i4 & 63;
      const int xr = 2*r0 - 1 + rr;
      float4 vv = make_float4(0.f, 0.f, 0.f, 0.f);
      if (xr >= 0 && xr < H_) {
        vv = *reinterpret_cast<const float4*>(img + (size_t)xr*256 + off4*4);
        if (rr >= 1 && rr <= 32) {
          cnt += (fabsf(vv.x) > 0.5f) + (fabsf(vv.y) > 0.5f)
               + (fabsf(vv.z) > 0.5f) + (fabsf(vv.w) > 0.5f);
        }
        vv.x = (fabsf(vv.x) > 0.5f) ? vv.x : 0.f;
        vv.y = (fabsf(vv.y) > 0.5f) ? vv.y : 0.f;
        vv.z = (fabsf(vv.z) > 0.5f) ? vv.z : 0.f;
        vv.w = (fabsf(vv.w) > 0.5f) ? vv.w : 0.f;
      }
      *reinterpret_cast<float4*>(&xt[i4*4]) = vv;
    }
    __syncthreads();
    // ---- patch scores ----
    {
      const int patch = tid >> 2, q = tid & 3;
      const int prl = patch >> 4, pc = patch & 15;
      const int row = 1 + prl*8 + q*2;
      float s = 0.f;
#pragma unroll
      for (int r2 = 0; r2 < 2; ++r2)
#pragma unroll
        for (int j = 0; j < 4; ++j) {
          const float4 vv = *reinterpret_cast<const float4*>(&xt[(row + r2)*256 + pc*16 + j*4]);
          s += fabsf(vv.x) + fabsf(vv.y) + fabsf(vv.z) + fabsf(vv.w);
        }
      s += __shfl_down(s, 1);
      s += __shfl_down(s, 2);
      if (q == 0) {
        const float sv = s * (1.f/128.f);
        sm[chunk*64 + patch] = sv;
        scores_g[tb*NP_ + chunk*64 + patch] = sv;
      }
    }
    // ---- padded downsample (f2 over channel pair) ----
    float* Pt = P + (size_t)tb * PTB;
    if (tid < 128) {
      const int r = tid >> 3, rem = tid & 7;
      const int px4 = rem >> 1, ci = rem & 1;
      const int px = (px4 < 2) ? (px4 - 2) : (62 + px4);
      Pt[(r0 + r + 1)*PROW + (px + 2)*2 + ci] = 0.f;
    }
    if (chunk == 0 && tid < PROW) Pt[tid] = 0.f;
    if (chunk == 3 && tid < PROW) Pt[65*PROW + tid] = 0.f;
#pragma unroll
    for (int k = 0; k < 4; ++k) {
      const int idx = k*256 + tid;       // f2 output: row16*64 + col
      const int col = idx & 63, row16 = idx >> 6;
      const int pr = r0 + row16;
      float wy0=0.125f, wy1=0.375f, wy2=0.375f, wy3=0.125f;
      if (pr == 0)       { wy0=0.f;     wy1=3.f/7.f; wy2=3.f/7.f; wy3=1.f/7.f; }
      else if (pr == 63) { wy0=1.f/7.f; wy1=3.f/7.f; wy2=3.f/7.f; wy3=0.f; }
      float wx0=0.125f, wx1=0.375f, wx2=0.375f, wx3=0.125f;
      if (col == 0)       { wx0=0.f;     wx1=3.f/7.f; wx2=3.f/7.f; wx3=1.f/7.f; }
      else if (col == 63) { wx0=1.f/7.f; wx1=3.f/7.f; wx2=3.f/7.f; wx3=0.f; }
      const int lr = 2*row16;
      const int cc0 = 2*col - 1;
      f2 val = (f2)0.f;
#pragma unroll
      for (int j = 0; j < 4; ++j) {
        const float wyj = (j==0)?wy0:(j==1)?wy1:(j==2)?wy2:wy3;
        f2 h = (f2)0.f;
#pragma unroll
        for (int i = 0; i < 4; ++i) {
          const float wxi = (i==0)?wx0:(i==1)?wx1:(i==2)?wx2:wx3;
          int cc = cc0 + i; cc = cc < 0 ? 0 : (cc > W_-1 ? W_-1 : cc);
          const f2 xv = *reinterpret_cast<const f2*>(&xt[(lr + j)*256 + cc*2]);
          h += wxi * xv;
        }
        val += wyj * h;
      }
      *reinterpret_cast<f2*>(&Pt[(pr + 1)*PROW + (col + 2)*2]) = val;
    }
  }
  // ---- event-count reduce ----
  unsigned c64 = cnt;
#pragma unroll
  for (int off = 32; off > 0; off >>= 1) c64 += __shfl_down(c64, off);
  if ((tid & 63) == 0) wsum[tid >> 6] = c64;
  __syncthreads();
  if (tid == 0) atomicAdd(&cnts[0], wsum[0] + wsum[1] + wsum[2] + wsum[3]);
  // ---- top-4 threshold + first-index argmax (tournament) ----
  {
    const float sv_ = sm[tid];
    const int wv = tid >> 6, ln = tid & 63;
    bool masked = false;
    float v4 = 0.f;
    for (int r = 0; r < 4; ++r) {
      float cur = masked ? -1e30f : sv_;
      float m = cur;
#pragma unroll
      for (int off = 32; off > 0; off >>= 1) m = fmaxf(m, __shfl_xor(m, off));
      if (ln == 0) wred[wv] = m;
      __syncthreads();
      const float bm = fmaxf(fmaxf(wred[0], wred[1]), fmaxf(wred[2], wred[3]));
      const unsigned long long eq = __ballot(cur == bm);
      if (ln == 0) widx[wv] = eq ? (wv*64 + (int)(__ffsll((long long)eq) - 1)) : 1024;
      __syncthreads();
      const int first = min(min(widx[0], widx[1]), min(widx[2], widx[3]));
      if (tid == first) {
        masked = true;
        if (r == 0) {
          const int cy = (tid >> 4)*8 + 4, cx = (tid & 15)*8 + 4;
          int y0 = cy - 16; y0 = y0 < 0 ? 0 : (y0 > 96 ? 96 : y0);
          int x0 = cx - 16; x0 = x0 < 0 ? 0 : (x0 > 96 ? 96 : x0);
          syx = make_int2(y0, x0);
        }
      }
      if (r == 3) v4 = bm;
      __syncthreads();
    }
    if (sv_ >= v4) atomicAdd(&cnts[1 + tid], 1u);
  }
  // ---- zero fovea tile (reuse xt as tile[34*68]) ----
  float* tile = xt;
  for (int i = tid; i < 34*68; i += 256) tile[i] = 0.f;
  __syncthreads();
  const int2 yx = syx;
  {                                     // fill interior: 32 rows x 8 segs x 4px
    const int row = tid >> 3, seg = tid & 7;
    const float* src = img + (size_t)(yx.x + row)*256 + (yx.y + seg*4)*2;
    float4 a = *reinterpret_cast<const float4*>(src);
    float4 b4 = *reinterpret_cast<const float4*>(src + 4);
    a.x  = (fabsf(a.x)  > 0.5f) ? a.x  : 0.f;
    a.y  = (fabsf(a.y)  > 0.5f) ? a.y  : 0.f;
    a.z  = (fabsf(a.z)  > 0.5f) ? a.z  : 0.f;
    a.w  = (fabsf(a.w)  > 0.5f) ? a.w  : 0.f;
    b4.x = (fabsf(b4.x) > 0.5f) ? b4.x : 0.f;
    b4.y = (fabsf(b4.y) > 0.5f) ? b4.y : 0.f;
    b4.z = (fabsf(b4.z) > 0.5f) ? b4.z : 0.f;
    b4.w = (fabsf(b4.w) > 0.5f) ? b4.w : 0.f;
    float* dst = &tile[(row + 1)*68 + (seg*4 + 1)*2];
    *reinterpret_cast<float2*>(dst)     = make_float2(a.x, a.y);
    *reinterpret_cast<float2*>(dst + 2) = make_float2(a.z, a.w);
    *reinterpret_cast<float2*>(dst + 4) = make_float2(b4.x, b4.y);
    *reinterpret_cast<float2*>(dst + 6) = make_float2(b4.z, b4.w);
  }
  __syncthreads();
  {                                     // dump padded masked window for k_mem
    float* dst = Wfbuf + (size_t)tb*WTB;
    for (int i = tid; i < WTB/4; i += 256)
      *reinterpret_cast<float4*>(dst + i*4) = *reinterpret_cast<const float4*>(&tile[i*4]);
  }
  // ---- fovea conv -> saliency (pk-f32, 2ch/thread, 4px groups) ----
  const int cp2 = tid & 31, xg = tid >> 5;       // ch-pair, x-group of 4 px
  const int c0 = cp2*2;
  f2 wxr[9], wyr[9];
#pragma unroll
  for (int j = 0; j < 9; ++j) {
    wxr[j] = *reinterpret_cast<const f2*>(&wf[(2*j)*CF_ + c0]);
    wyr[j] = *reinterpret_cast<const f2*>(&wf[(2*j + 1)*CF_ + c0]);
  }
  const float* tbase = &tile[xg*8];
  float4 wb[3][3];
#pragma unroll
  for (int m = 0; m < 3; ++m) {
    wb[0][m] = *reinterpret_cast<const float4*>(tbase + m*4);
    wb[1][m] = *reinterpret_cast<const float4*>(tbase + 68 + m*4);
  }
  f2 sal = (f2)0.f;
#pragma unroll
  for (int yy = 0; yy < 32; ++yy) {
#pragma unroll
    for (int m = 0; m < 3; ++m)
      wb[(yy+2)%3][m] = *reinterpret_cast<const float4*>(tbase + (yy+2)*68 + m*4);
#pragma unroll
    for (int k = 0; k < 4; ++k) {
      f2 acc = (f2)0.f;
#pragma unroll
      for (int dy = 0; dy < 3; ++dy) {
#pragma unroll
        for (int dx = 0; dx < 3; ++dx) {
          const int r = k + dx;
          const float4 f = wb[(yy+dy)%3][r >> 1];
          acc += f4c(f, (r&1)*2)     * wxr[dy*3+dx]
               + f4c(f, (r&1)*2 + 1) * wyr[dy*3+dx];
        }
      }
      sal.x += fabsf(acc.x);
      sal.y += fabsf(acc.y);
    }
  }
  salred[xg*64 + c0]     = sal.x;
  salred[xg*64 + c0 + 1] = sal.y;
  __syncthreads();
  if (tid < 64) {
    float s = 0.f;
#pragma unroll
    for (int g = 0; g < 8; ++g) s += salred[g*64 + tid];
    salv[tid] = s * (1.f/1024.f);
  }
  __syncthreads();
  if (tid < 64) {
    const float sv = salv[tid];
    int cg = 0;
    for (int q = 0; q < 64; ++q) cg += (salv[q] > sv) ? 1 : 0;
    const float gate = (cg < 16) ? 1.f : 0.f;
    chan_gate[tb*CF_ + tid] = gate;
    if (gate > 0.f) atomicAdd(&cnts[257 + tid], 1u);
  }
}

// ---------------- K2: persistent membranes, LDS slab dbuf, 4 ch/thread, VGPR weights (pk-f32) ----------------
// periph: blocks 0..2047    = b*64 + cp*8 + rq (cp 0..7, 4ch each); slab 10x136 (launched first)
// fovea:  blocks 2048..3071 = 2048 + b*32 + cp*2 + half (cp 0..15, 4ch each); slab 18x68
__global__ void __launch_bounds__(256, 2) k_mem(const float* __restrict__ Wfbuf,
    const float* __restrict__ P, const float* __restrict__ wf, const float* __restrict__ wp,
    const float* __restrict__ chan_gate,
    unsigned* __restrict__ fov_part, unsigned* __restrict__ per_part) {
  __shared__ __align__(16) float lds[2*1360];
  const int tid = threadIdx.x;
  const int w = tid >> 6, l = tid & 63;
  int zp;                               // opaque zero: forces weight/gate loads into VGPRs
  asm volatile("v_mov_b32 %0, 0" : "=v"(zp));
  if (blockIdx.x >= 2048) {
    const int blk = blockIdx.x - 2048;
    const int b = blk >> 5, rem = blk & 31, cp = rem >> 1, half = rem & 1;
    const int ch0 = cp*4;
    const int brow = w*4 + (l >> 4);
    const int po = (l & 15)*4;
    f2 w01[18], w23[18];
#pragma unroll
    for (int k = 0; k < 18; ++k) {
      w01[k] = *reinterpret_cast<const f2*>(&wf[k*CF_ + ch0 + zp]);
      w23[k] = *reinterpret_cast<const f2*>(&wf[k*CF_ + ch0 + zp + 2]);
    }
    const float* gsrc = Wfbuf + (size_t)b*WTB + half*16*68;   // 1224 floats/slab
    const float* gp = chan_gate + b*CF_ + ch0 + zp;
    const unsigned ob01 = (unsigned)((b*32 + cp*2)*8 + half*4 + w);
    f2 va01 = (f2)0.f, vb01 = (f2)0.f, va23 = (f2)0.f, vb23 = (f2)0.f;
    float4 r0, r1;
    r0 = *reinterpret_cast<const float4*>(gsrc + tid*4);
    if (tid < 50) r1 = *reinterpret_cast<const float4*>(gsrc + (tid + 256)*4);
    *reinterpret_cast<float4*>(&lds[tid*4]) = r0;
    if (tid < 50) *reinterpret_cast<float4*>(&lds[(tid + 256)*4]) = r1;
    int cur = 0;
    for (int t = 0; t < T_; ++t) {
      __syncthreads();                  // slab[cur] visible to all
      if (t + 1 < T_) {                 // issue next slab's loads early
        const float* gn = gsrc + (size_t)(t + 1)*(B_*WTB);
        r0 = *reinterpret_cast<const float4*>(gn + tid*4);
        if (tid < 50) r1 = *reinterpret_cast<const float4*>(gn + (tid + 256)*4);
      }
      __builtin_amdgcn_sched_barrier(0);
      const f2 g01 = *reinterpret_cast<const f2*>(gp + (size_t)t*B_*CF_);
      const f2 g23 = *reinterpret_cast<const f2*>(gp + (size_t)t*B_*CF_ + 2);
      const float* Lb = &lds[cur*1360];
      f2 aa01 = (f2)0.f, ab01 = (f2)0.f, aa23 = (f2)0.f, ab23 = (f2)0.f;
#pragma unroll
      for (int dy = 0; dy < 3; ++dy) {
        const float4 fa = *reinterpret_cast<const float4*>(Lb + (brow + dy)*68 + po);
        const float4 fb = *reinterpret_cast<const float4*>(Lb + (brow + dy)*68 + po + 4);
        {
          const f2 w0 = w01[dy*6], w0y = w01[dy*6+1], w1 = w01[dy*6+2],
                   w1y = w01[dy*6+3], w2 = w01[dy*6+4], w2y = w01[dy*6+5];
          aa01 += fa.x*w0 + fa.y*w0y + fa.z*w1 + fa.w*w1y + fb.x*w2 + fb.y*w2y;
          ab01 += fa.z*w0 + fa.w*w0y + fb.x*w1 + fb.y*w1y + fb.z*w2 + fb.w*w2y;
        }
        {
          const f2 w0 = w23[dy*6], w0y = w23[dy*6+1], w1 = w23[dy*6+2],
                   w1y = w23[dy*6+3], w2 = w23[dy*6+4], w2y = w23[dy*6+5];
          aa23 += fa.x*w0 + fa.y*w0y + fa.z*w1 + fa.w*w1y + fb.x*w2 + fb.y*w2y;
          ab23 += fa.z*w0 + fa.w*w0y + fb.x*w1 + fb.y*w1y + fb.z*w2 + fb.w*w2y;
        }
      }
      f2 na01 = 0.9f*va01 + aa01*g01;
      f2 nb01 = 0.9f*vb01 + ab01*g01;
      f2 na23 = 0.9f*va23 + aa23*g23;
      f2 nb23 = 0.9f*vb23 + ab23*g23;
      const bool s0a = na01.x > 1.f, s1a = na01.y > 1.f, s0b = nb01.x > 1.f, s1b = nb01.y > 1.f;
      const bool s2a = na23.x > 1.f, s3a = na23.y > 1.f, s2b = nb23.x > 1.f, s3b = nb23.y > 1.f;
      va01.x = s0a ? na01.x - 1.f : na01.x;  va01.y = s1a ? na01.y - 1.f : na01.y;
      vb01.x = s0b ? nb01.x - 1.f : nb01.x;  vb01.y = s1b ? nb01.y - 1.f : nb01.y;
      va23.x = s2a ? na23.x - 1.f : na23.x;  va23.y = s3a ? na23.y - 1.f : na23.y;
      vb23.x = s2b ? nb23.x - 1.f : nb23.x;  vb23.y = s3b ? nb23.y - 1.f : nb23.y;
      const unsigned p01 =
          (unsigned)(__popcll(__ballot(s0a)) + __popcll(__ballot(s0b)))
        | ((unsigned)(__popcll(__ballot(s1a)) + __popcll(__ballot(s1b))) << 16);
      const unsigned p23 =
          (unsigned)(__popcll(__ballot(s2a)) + __popcll(__ballot(s2b)))
        | ((unsigned)(__popcll(__ballot(s3a)) + __popcll(__ballot(s3b))) << 16);
      if (l == 0) {
        fov_part[ob01 + (unsigned)t*8192u]     = p01;
        fov_part[ob01 + 8 + (unsigned)t*8192u] = p23;
      }
      if (t + 1 < T_) {                 // write staged regs to other buffer
        float* Lw = &lds[(cur ^ 1)*1360];
        *reinterpret_cast<float4*>(Lw + tid*4) = r0;
        if (tid < 50) *reinterpret_cast<float4*>(Lw + (tid + 256)*4) = r1;
      }
      cur ^= 1;
    }
  } else {
    const int blk = blockIdx.x;
    const int b = blk >> 6, rem = blk & 63, cp = rem >> 3, rq = rem & 7;
    const int ch0 = cp*4;
    const int brow = w*2 + (l >> 5);
    const int po = (l & 31)*4;
    f2 w01[18], w23[18];
#pragma unroll
    for (int k = 0; k < 18; ++k) {
      w01[k] = *reinterpret_cast<const f2*>(&wp[k*CP_ + ch0 + zp]);
      w23[k] = *reinterpret_cast<const f2*>(&wp[k*CP_ + ch0 + zp + 2]);
    }
    const float* gsrc = P + (size_t)b*PTB + rq*8*PROW;        // 1360 floats/slab
    const unsigned ob01 = (unsigned)((b*16 + cp*2)*32 + rq*4 + w);
    f2 va01 = (f2)0.f, vb01 = (f2)0.f, va23 = (f2)0.f, vb23 = (f2)0.f;
    float4 r0, r1;
    r0 = *reinterpret_cast<const float4*>(gsrc + tid*4);
    if (tid < 84) r1 = *reinterpret_cast<const float4*>(gsrc + (tid + 256)*4);
    *reinterpret_cast<float4*>(&lds[tid*4]) = r0;
    if (tid < 84) *reinterpret_cast<float4*>(&lds[(tid + 256)*4]) = r1;
    int cur = 0;
    for (int t = 0; t < T_; ++t) {
      __syncthreads();
      if (t + 1 < T_) {
        const float* gn = gsrc + (size_t)(t + 1)*(B_*PTB);
        r0 = *reinterpret_cast<const float4*>(gn + tid*4);
        if (tid < 84) r1 = *reinterpret_cast<const float4*>(gn + (tid + 256)*4);
      }
      __builtin_amdgcn_sched_barrier(0);
      const float* Lb = &lds[cur*1360];
      f2 aa01 = (f2)0.f, ab01 = (f2)0.f, aa23 = (f2)0.f, ab23 = (f2)0.f;
#pragma unroll
      for (int dy = 0; dy < 3; ++dy) {
        const float4 f0 = *reinterpret_cast<const float4*>(Lb + (brow + dy)*136 + po);
        const float4 f1 = *reinterpret_cast<const float4*>(Lb + (brow + dy)*136 + po + 4);
        const float4 f2v = *reinterpret_cast<const float4*>(Lb + (brow + dy)*136 + po + 8);
        {
          const f2 w0 = w01[dy*6], w0y = w01[dy*6+1], w1 = w01[dy*6+2],
                   w1y = w01[dy*6+3], w2 = w01[dy*6+4], w2y = w01[dy*6+5];
          aa01 += f0.z*w0 + f0.w*w0y + f1.x*w1 + f1.y*w1y + f1.z*w2 + f1.w*w2y;
          ab01 += f1.x*w0 + f1.y*w0y + f1.z*w1 + f1.w*w1y + f2v.x*w2 + f2v.y*w2y;
        }
        {
          const f2 w0 = w23[dy*6], w0y = w23[dy*6+1], w1 = w23[dy*6+2],
                   w1y = w23[dy*6+3], w2 = w23[dy*6+4], w2y = w23[dy*6+5];
          aa23 += f0.z*w0 + f0.w*w0y + f1.x*w1 + f1.y*w1y + f1.z*w2 + f1.w*w2y;
          ab23 += f1.x*w0 + f1.y*w0y + f1.z*w1 + f1.w*w1y + f2v.x*w2 + f2v.y*w2y;
        }
      }
      f2 na01 = 0.9f*va01 + aa01;
      f2 nb01 = 0.9f*vb01 + ab01;
      f2 na23 = 0.9f*va23 + aa23;
      f2 nb23 = 0.9f*vb23 + ab23;
      const bool s0a = na01.x > 1.f, s1a = na01.y > 1.f, s0b = nb01.x > 1.f, s1b = nb01.y > 1.f;
      const bool s2a = na23.x > 1.f, s3a = na23.y > 1.f, s2b = nb23.x > 1.f, s3b = nb23.y > 1.f;
      va01.x = s0a ? na01.x - 1.f : na01.x;  va01.y = s1a ? na01.y - 1.f : na01.y;
      vb01.x = s0b ? nb01.x - 1.f : nb01.x;  vb01.y = s1b ? nb01.y - 1.f : nb01.y;
      va23.x = s2a ? na23.x - 1.f : na23.x;  va23.y = s3a ? na23.y - 1.f : na23.y;
      vb23.x = s2b ? nb23.x - 1.f : nb23.x;  vb23.y = s3b ? nb23.y - 1.f : nb23.y;
      const unsigned p01 =
          (unsigned)(__popcll(__ballot(s0a)) + __popcll(__ballot(s0b)))
        | ((unsigned)(__popcll(__ballot(s1a)) + __popcll(__ballot(s1b))) << 16);
      const unsigned p23 =
          (unsigned)(__popcll(__ballot(s2a)) + __popcll(__ballot(s2b)))
        | ((unsigned)(__popcll(__ballot(s3a)) + __popcll(__ballot(s3b))) << 16);
      if (l == 0) {
        per_part[ob01 + (unsigned)t*16384u]      = p01;
        per_part[ob01 + 32 + (unsigned)t*16384u] = p23;
      }
      if (t + 1 < T_) {
        float* Lw = &lds[(cur ^ 1)*1360];
        *reinterpret_cast<float4*>(Lw + tid*4) = r0;
        if (tid < 84) *reinterpret_cast<float4*>(Lw + (tid + 256)*4) = r1;
      }
      cur ^= 1;
    }
  }
}

// ---------------- K3: reduce partials + logits ----------------
__global__ void __launch_bounds__(256) k_logits(const float* __restrict__ scores,
    const unsigned* __restrict__ fov_part, const unsigned* __restrict__ per_part,
    const float* __restrict__ head_w, const float* __restrict__ head_b,
    const float* __restrict__ route_w, const float* __restrict__ route_b,
    float* __restrict__ logits, unsigned* __restrict__ tot) {
  const int tb = blockIdx.x, tid = threadIdx.x;
  __shared__ float sc[NP_];
  __shared__ float fu[96];
  sc[tid] = scores[tb*NP_ + tid];
  if (tid < 64) {
    const unsigned* fp = fov_part + (size_t)tb*256;   // 32 cp * 8
    const int cp = tid >> 1, sh = (tid & 1)*16;
    unsigned fsum = 0;
#pragma unroll
    for (int i = 0; i < 8; ++i) fsum += (fp[cp*8 + i] >> sh) & 0xFFFFu;
    fu[tid] = (float)fsum * (1.f/1024.f);
    unsigned r = fsum;
#pragma unroll
    for (int off = 32; off > 0; off >>= 1) r += __shfl_down(r, off);
    if (tid == 0) atomicAdd(&tot[0], r);
  } else if (tid < 128) {
    const int c = tid - 64;            // only c<32 active
    unsigned psum = 0;
    if (c < 32) {
      const unsigned* pp = per_part + (size_t)tb*512;  // 16 cp * 32
      const int cp = c >> 1, sh = (c & 1)*16;
#pragma unroll 8
      for (int i = 0; i < 32; ++i) psum += (pp[cp*32 + i] >> sh) & 0xFFFFu;
      fu[64 + c] = (float)psum * (1.f/4096.f);
    }
    unsigned r = psum;
#pragma unroll
    for (int off = 32; off > 0; off >>= 1) r += __shfl_down(r, off);
    if (tid == 64) atomicAdd(&tot[1], r);
  }
  __syncthreads();
  if (tid < 128) {
    const int o = tid;
    float acc = head_b[o] + route_b[o];
#pragma unroll 8
    for (int k = 0; k < 96; ++k)  acc += fu[k]*head_w[k*OUT_ + o];
#pragma unroll 8
    for (int p = 0; p < NP_; ++p) acc += sc[p]*route_w[p*OUT_ + o];
    logits[tb*OUT_ + o] = acc;
  }
}

// ---------------- K4: finalize ----------------
__global__ void __launch_bounds__(256) k_final(const float* __restrict__ logits,
    float* __restrict__ dout, const unsigned* __restrict__ cnts) {
  const int blk = blockIdx.x, tid = threadIdx.x;
  if (blk < 16) {
    const int idx = blk*256 + tid;
    const int b = idx >> 7, o = idx & 127;
    float s = 0.f;
#pragma unroll
    for (int t = 0; t < T_; ++t) s += logits[(t*B_ + b)*OUT_ + o];
    dout[idx] = s * (1.f/32.f);
  } else {
    if (tid == 0) {
      dout[OFF_SR]     = (float)cnts[321] * (1.f/67108864.f);   // T*B*32*32*64
      dout[OFF_SR + 1] = (float)cnts[322] * (1.f/134217728.f);  // T*B*64*64*32
      dout[OFF_ACTIVE] = (float)cnts[0]   * (1.f/33554432.f);   // T*B*H*W*C
    }
    dout[OFF_ROUTE + tid] = (float)cnts[1 + tid] * (1.f/1024.f);
    if (tid < 64) dout[OFF_CHAN + tid] = (float)cnts[257 + tid] * (1.f/1024.f);
  }
}

extern "C" void kernel_launch(void* const* d_in, const int* in_sizes, int n_in,
                              void* d_out, int out_size, void* d_ws, size_t ws_size,
                              hipStream_t stream) {
  const float* x       = (const float*)d_in[0];
  const float* wf      = (const float*)d_in[1];
  const float* wp      = (const float*)d_in[2];
  const float* head_w  = (const float*)d_in[3];
  const float* head_b  = (const float*)d_in[4];
  const float* route_w = (const float*)d_in[5];
  const float* route_b = (const float*)d_in[6];
  float* out = (float*)d_out;

  float*    ws_P      = (float*)d_ws;                         // 1024*8976 floats (36.8 MB)
  float*    ws_Wf     = ws_P + (size_t)1024*PTB;              // 1024*2312 floats (9.5 MB)
  float*    ws_scores = ws_Wf + (size_t)1024*WTB;             // 262144 floats
  float*    ws_gate   = ws_scores + T_*B_*NP_;                // 65536 floats
  unsigned* fov_part  = (unsigned*)(ws_gate + T_*B_*CF_);     // 32*32*32*8 u32 (1 MB)
  unsigned* per_part  = fov_part + (size_t)T_*B_*256;         // 32*32*16*32 u32 (2 MB)
  unsigned* ws_cnt    = per_part + (size_t)T_*B_*512;

  hipMemsetAsync(ws_cnt, 0, CNT_N*sizeof(unsigned), stream);

  k_pre   <<<T_*B_, 256, 0, stream>>>(x, wf, ws_scores, ws_P, ws_Wf, ws_gate, ws_cnt);
  k_mem   <<<3072,  256, 0, stream>>>(ws_Wf, ws_P, wf, wp, ws_gate, fov_part, per_part);
  k_logits<<<T_*B_, 256, 0, stream>>>(ws_scores, fov_part, per_part, head_w, head_b,
                                      route_w, route_b, out + OFF_LOGITS, ws_cnt + 321);
  k_final <<<17, 256, 0, stream>>>(out + OFF_LOGITS, out, ws_cnt);
}